// Round 3
// baseline (166.406 us; speedup 1.0000x reference)
//
#include <hip/hip_runtime.h>

#define BB 2
#define SS 128
#define HH 1024
#define AA 256
#define CC 14
#define R_TOT (BB*SS)   // 256 rows per net

struct NetP { const float *W1,*b1,*W2,*b2,*s0W,*s0b,*s1W,*s1b; };
struct AllP { NetP n[3]; };

// ws float offsets
#define S0_OFF 0                         // [3][256][14]
#define S1_OFF (3*R_TOT*CC)              // 10752
#define P_OFF  (2*3*R_TOT*CC)            // 21504  [2][129][14]
#define Q_OFF  (P_OFF + BB*(SS+1)*CC)    // 25116
#define MEAN_OFF (Q_OFF + BB*(SS+1)*CC)  // 28728  [2][14]
#define FLAG_OFF 29056                   // 128 uints (recast region)
#define HID_OFF  32768                   // [3][256][256] = 768 KB

#define N_HID_BLK 384
#define N_OUT_BLK 192
#define N_FIN_BLK 256
// flags: [0..95] cnt_hid[net*32+rt8], [96] out_done, [97] prefix_flag

__global__ void zero_flags(unsigned* __restrict__ f)
{
    if (threadIdx.x < 128) f[threadIdx.x] = 0u;
}

// ---------------------------------------------------------------------------
// One dispatch does everything:
//  H: hid[net][row][a] = relu(mem@W1+b1)     (384 tiles: 8 rows x 64 cols, 8-wave K-split)
//  O: outp = hid@W2+b2; s0,s1 projections    (192 tiles: 4 rows x 256 cols)
//  prefix: per (b,c) max/exp prefix sums     (done by the 192nd O-finisher)
//  F: out[b,i,j,c] = sh1+st1+uni + softmax-weighted-mean term  (256 tiles)
// Cross-block deps via AGENT-scope flags; all 384 blocks co-resident
// (__launch_bounds__(512,4) -> VGPR<=128 -> >=2 blocks/CU).
// ---------------------------------------------------------------------------
__global__ __launch_bounds__(512, 4)
void mega_kernel(const float* __restrict__ mem, AllP P,
                 const float* __restrict__ uni,
                 float* __restrict__ ws, float* __restrict__ out)
{
    float* s0o = ws + S0_OFF;
    float* s1o = ws + S1_OFF;
    float* Pp  = ws + P_OFF;
    float* Qp  = ws + Q_OFF;
    float* mnp = ws + MEAN_OFF;
    unsigned* flags = (unsigned*)(ws + FLAG_OFF);
    float* hid = ws + HID_OFF;

    const int bid  = blockIdx.x;
    const int tid  = threadIdx.x;
    const int lane = tid & 63;
    const int wv   = __builtin_amdgcn_readfirstlane(tid >> 6);

    __shared__ __align__(16) char smem[16896];
    __shared__ unsigned sh_n;

    // ---------------- Phase H : layer-1 GEMM ----------------
    {
        const int net = bid >> 7;          // 0..2
        const int rem = bid & 127;
        const int rt8 = rem >> 2;          // 0..31 (8-row tiles)
        const int ct  = rem & 3;           // 0..3  (64-col tiles)
        const int row0 = rt8 * 8;
        const int col  = ct*64 + lane;
        const NetP p = P.n[net];
        float (*part)[8][64] = (float(*)[8][64])smem;   // 16 KB

        float acc[8] = {0,0,0,0,0,0,0,0};
        const int k0 = wv * 128;
        const float* __restrict__ W1p  = p.W1 + (size_t)k0*AA + col;
        const float* __restrict__ memp = mem + (size_t)row0*HH + k0;  // shared across nets
        #pragma unroll 8
        for (int kk = 0; kk < 128; ++kk) {
            const float w = W1p[(size_t)kk*AA];
            #pragma unroll
            for (int r = 0; r < 8; ++r)
                acc[r] = fmaf(memp[(size_t)r*HH + kk], w, acc[r]);  // wave-uniform -> s_load
        }
        #pragma unroll
        for (int r = 0; r < 8; ++r) part[wv][r][lane] = acc[r];
        __syncthreads();
        const int r = tid >> 6;
        float s = p.b1[ct*64 + lane];
        #pragma unroll
        for (int w = 0; w < 8; ++w) s += part[w][r][lane];
        hid[((size_t)net*R_TOT + row0 + r)*AA + ct*64 + lane] = fmaxf(s, 0.f);
        __syncthreads();   // all hid stores drained (vmcnt0 before barrier)
        if (tid == 0) {
            __threadfence();
            __hip_atomic_fetch_add(&flags[net*32 + rt8], 1u,
                                   __ATOMIC_RELEASE, __HIP_MEMORY_SCOPE_AGENT);
        }
    }

    // ---------------- Phase O : layer-2 GEMM + projections ----------------
    if (bid < N_OUT_BLK) {
        const int net = bid >> 6;          // 0..2
        const int rt4 = bid & 63;          // 4-row tiles
        const int row0 = rt4 * 4;
        const NetP p = P.n[net];
        if (tid == 0) {
            while (__hip_atomic_load(&flags[net*32 + (rt4 >> 1)],
                                     __ATOMIC_ACQUIRE, __HIP_MEMORY_SCOPE_AGENT) < 4u)
                __builtin_amdgcn_s_sleep(8);
        }
        __syncthreads();

        float (*part2)[4][256] = (float(*)[4][256])smem;             // 8 KB
        float (*outp)[256]     = (float(*)[256])(smem + 8192);       // 4 KB
        float (*pp)[4]         = (float(*)[4])(smem + 8192 + 4096);  // 1.75 KB

        const int col = tid & 255;
        const int kh  = tid >> 8;          // 0/1
        const float* __restrict__ hb = hid + ((size_t)net*R_TOT + row0)*AA;
        float acc2[4] = {0,0,0,0};
        const int k0 = kh * 128;
        const float* __restrict__ W2p = p.W2 + (size_t)k0*AA + col;
        #pragma unroll 8
        for (int kk = 0; kk < 128; ++kk) {
            const float w = W2p[(size_t)kk*AA];
            #pragma unroll
            for (int r = 0; r < 4; ++r)
                acc2[r] = fmaf(hb[(size_t)r*AA + k0 + kk], w, acc2[r]);  // uniform -> s_load
        }
        #pragma unroll
        for (int r = 0; r < 4; ++r) part2[kh][r][col] = acc2[r];
        __syncthreads();
        for (int i2 = tid; i2 < 4*AA; i2 += 512) {
            const int r = i2 >> 8, u = i2 & 255;
            outp[r][u] = part2[0][r][u] + part2[1][r][u] + p.b2[u];
        }
        __syncthreads();
        if (tid < 448) {
            const int task = tid >> 2, kc = tid & 3;
            const int which = (task >= 56) ? 1 : 0;
            const int rem2  = task - which*56;
            const int rr = rem2 / CC, c = rem2 % CC;
            const float* __restrict__ W = which ? p.s1W : p.s0W;
            float s = 0.f;
            #pragma unroll 4
            for (int k = kc*64; k < kc*64 + 64; ++k)
                s = fmaf(outp[rr][k], W[(size_t)k*CC + c], s);
            pp[task][kc] = s;
        }
        __syncthreads();
        if (tid < 112) {
            const int which = (tid >= 56) ? 1 : 0;
            const int rem2  = tid - which*56;
            const int rr = rem2 / CC, c = rem2 % CC;
            const float s = pp[tid][0]+pp[tid][1]+pp[tid][2]+pp[tid][3]
                          + (which ? p.s1b : p.s0b)[c];
            (which ? s1o : s0o)[((size_t)net*R_TOT + row0 + rr)*CC + c] = s;
        }
        __syncthreads();
        if (tid == 0) {
            __threadfence();
            sh_n = __hip_atomic_fetch_add(&flags[96], 1u,
                                          __ATOMIC_ACQ_REL, __HIP_MEMORY_SCOPE_AGENT) + 1u;
        }
        __syncthreads();

        // -------- prefix scan: exactly one block (the last O-finisher) --------
        if (sh_n == N_OUT_BLK) {
            float (*red)[4][2] = (float(*)[4][2])smem;  // [kind][slot][wave]
            const int slot = tid >> 7;                  // 4 (b,c)-pairs per pass
            const int k    = tid & 127;
            const int wv2  = (tid >> 6) & 1;
            for (int base = 0; base < BB*CC; base += 4) {
                const int pair = base + slot;           // < 28
                const int b = pair / CC, c = pair % CC;
                const float x0 = s0o[(size_t)(2*R_TOT + b*SS + k)*CC + c];
                const float x1 = s1o[(size_t)(2*R_TOT + b*SS + k)*CC + c];
                float m = x0;
                #pragma unroll
                for (int off = 32; off >= 1; off >>= 1) m = fmaxf(m, __shfl_xor(m, off));
                float ssum = x1;
                #pragma unroll
                for (int off = 32; off >= 1; off >>= 1) ssum += __shfl_xor(ssum, off);
                if (lane == 0) { red[0][slot][wv2] = m; red[1][slot][wv2] = ssum; }
                __syncthreads();
                const float M = fmaxf(red[0][slot][0], red[0][slot][1]);
                float e = __expf(x0 - M);
                float q = e * x1;
                #pragma unroll
                for (int off = 1; off <= 32; off <<= 1) {
                    const float te = __shfl_up(e, off);
                    const float tq = __shfl_up(q, off);
                    if (lane >= off) { e += te; q += tq; }
                }
                if (lane == 63) { red[2][slot][wv2] = e; red[3][slot][wv2] = q; }
                __syncthreads();
                if (wv2 == 1) { e += red[2][slot][0]; q += red[3][slot][0]; }
                const size_t pb = ((size_t)b*(SS+1))*CC + c;
                Pp[pb + (size_t)(k+1)*CC] = e;
                Qp[pb + (size_t)(k+1)*CC] = q;
                if (k == 0) {
                    Pp[pb] = 0.f; Qp[pb] = 0.f;
                    mnp[b*CC + c] = (red[1][slot][0] + red[1][slot][1]) * (1.f/SS);
                }
                __syncthreads();
            }
            if (tid == 0) {
                __threadfence();
                __hip_atomic_store(&flags[97], 1u,
                                   __ATOMIC_RELEASE, __HIP_MEMORY_SCOPE_AGENT);
            }
        }
    }

    // ---------------- Phase F : output fill ----------------
    if (bid < N_FIN_BLK) {
        if (tid == 0) {
            while (__hip_atomic_load(&flags[97],
                                     __ATOMIC_ACQUIRE, __HIP_MEMORY_SCOPE_AGENT) == 0u)
                __builtin_amdgcn_s_sleep(8);
        }
        __syncthreads();
        const int b = bid >> 7, i = bid & (SS-1);
        float* shf  = (float*)smem;
        float* sh1L = shf;       float* uniL = shf + 16;
        float* mnL  = shf + 32;  float* PiL  = shf + 48;  float* QiL = shf + 64;
        if (tid < CC) {
            const int c = tid;
            sh1L[c] = s1o[(size_t)bid*CC + c];
            uniL[c] = uni[c];
            mnL[c]  = mnp[b*CC + c];
            PiL[c]  = Pp[((size_t)b*(SS+1) + i)*CC + c];
            QiL[c]  = Qp[((size_t)b*(SS+1) + i)*CC + c];
        }
        __syncthreads();
        const float* __restrict__ st1 = s1o + (size_t)(R_TOT + b*SS)*CC;  // [j][c]
        const float* __restrict__ Pj  = Pp + ((size_t)b*(SS+1) + 1)*CC;
        const float* __restrict__ Qj  = Qp + ((size_t)b*(SS+1) + 1)*CC;
        float* __restrict__ o = out + (size_t)bid*SS*CC;
        for (int idx = tid; idx < SS*CC; idx += 512) {
            const int j = idx / CC, c = idx - j*CC;
            float add;
            if (i <= j) add = (Qj[idx] - QiL[c]) / (Pj[idx] - PiL[c]);
            else        add = mnL[c];
            o[idx] = sh1L[c] + st1[idx] + uniL[c] + add;
        }
    }
}

extern "C" void kernel_launch(void* const* d_in, const int* in_sizes, int n_in,
                              void* d_out, int out_size, void* d_ws, size_t ws_size,
                              hipStream_t stream)
{
    const float* mem = (const float*)d_in[0];
    AllP P;
    for (int n = 0; n < 3; ++n) {
        const int base = 1 + 8*n;
        P.n[n].W1  = (const float*)d_in[base+0];
        P.n[n].b1  = (const float*)d_in[base+1];
        P.n[n].W2  = (const float*)d_in[base+2];
        P.n[n].b2  = (const float*)d_in[base+3];
        P.n[n].s0W = (const float*)d_in[base+4];
        P.n[n].s0b = (const float*)d_in[base+5];
        P.n[n].s1W = (const float*)d_in[base+6];
        P.n[n].s1b = (const float*)d_in[base+7];
    }
    const float* uni = (const float*)d_in[25];
    float* ws  = (float*)d_ws;
    float* out = (float*)d_out;
    unsigned* flags = (unsigned*)(ws + FLAG_OFF);

    hipLaunchKernelGGL(zero_flags,  dim3(1),         dim3(128), 0, stream, flags);
    hipLaunchKernelGGL(mega_kernel, dim3(N_HID_BLK), dim3(512), 0, stream,
                       mem, P, uni, ws, out);
}

// Round 4
// 33.164 us; speedup vs baseline: 5.0176x; 5.0176x over previous
//
#include <hip/hip_runtime.h>

#define BB 2
#define SS 128
#define HH 1024
#define AA 256
#define CC 14
#define R_TOT (BB*SS)   // 256 rows per net

struct NetP { const float *W1,*b1,*W2,*b2,*s0W,*s0b,*s1W,*s1b; };
struct AllP { NetP n[3]; };

// ws float offsets
#define S0_OFF 0                         // [3][256][14]
#define S1_OFF (3*R_TOT*CC)
#define HID_OFF 32768                    // [3][256][256] = 768 KB

// ---------------------------------------------------------------------------
// K1: hid[net][row][a] = relu(mem[row]·W1[:,a] + b1[a])
// grid = net(3) * rowtile(32 of 8 rows) * coltile(4 of 64 cols) = 384 blocks
// 512 threads = 8 waves; wave w handles K-chunk [w*128, w*128+128)
// ---------------------------------------------------------------------------
__global__ __launch_bounds__(512)
void hid_kernel(const float* __restrict__ mem, AllP P, float* __restrict__ hid)
{
    const int bx  = blockIdx.x;
    const int net = bx >> 7;
    const int rem = bx & 127;
    const int rt  = rem >> 2;           // 0..31
    const int ct  = rem & 3;            // 0..3
    const int row0 = rt * 8;
    const int lane = threadIdx.x & 63;
    const int wv   = __builtin_amdgcn_readfirstlane(threadIdx.x >> 6); // 0..7
    const int col  = ct*64 + lane;
    const NetP p = P.n[net];

    __shared__ float part[8][8][64];    // 16 KB

    float acc[8] = {0,0,0,0,0,0,0,0};
    const int k0 = wv * 128;
    const float* __restrict__ W1p  = p.W1 + (size_t)k0*AA + col;
    const float* __restrict__ memp = mem + (size_t)row0*HH + k0;
    #pragma unroll 8
    for (int kk = 0; kk < 128; ++kk) {
        const float w = W1p[(size_t)kk*AA];
        #pragma unroll
        for (int r = 0; r < 8; ++r)
            acc[r] = fmaf(memp[(size_t)r*HH + kk], w, acc[r]);   // uniform -> s_load
    }
    #pragma unroll
    for (int r = 0; r < 8; ++r) part[wv][r][lane] = acc[r];
    __syncthreads();

    const int r = threadIdx.x >> 6;
    const int l = threadIdx.x & 63;
    float s = p.b1[ct*64 + l];
    #pragma unroll
    for (int w = 0; w < 8; ++w) s += part[w][r][l];
    hid[((size_t)net*R_TOT + row0 + r)*AA + ct*64 + l] = fmaxf(s, 0.f);
}

// ---------------------------------------------------------------------------
// K2: outp = hid@W2 + b2 (4 rows/block, 256 cols, K split 2-way), then fused
// projections s0 = outp@s0W+s0b, s1 = outp@s1W+s1b  (C=14)
// grid = net(3) * rowtile(64 of 4 rows) = 192 blocks, 512 threads
// ---------------------------------------------------------------------------
__global__ __launch_bounds__(512)
void out_kernel(const float* __restrict__ hid, AllP P,
                float* __restrict__ s0o, float* __restrict__ s1o)
{
    const int bx  = blockIdx.x;
    const int net = bx >> 6;
    const int rt  = bx & 63;
    const int row0 = rt * 4;
    const NetP p = P.n[net];
    const int col = threadIdx.x & 255;
    const int kh  = __builtin_amdgcn_readfirstlane(threadIdx.x >> 8); // 0/1

    __shared__ float part[2][4][256];   // 8 KB
    __shared__ float outp[4][256];      // 4 KB
    __shared__ float pp[112][4];        // 1.75 KB

    const float* __restrict__ hb = hid + ((size_t)net*R_TOT + row0)*AA;
    float acc[4] = {0,0,0,0};
    const int k0 = kh * 128;
    const float* __restrict__ W2p = p.W2 + (size_t)k0*AA + col;
    #pragma unroll 8
    for (int kk = 0; kk < 128; ++kk) {
        const float w = W2p[(size_t)kk*AA];
        #pragma unroll
        for (int r = 0; r < 4; ++r)
            acc[r] = fmaf(hb[(size_t)r*AA + k0 + kk], w, acc[r]);  // uniform -> s_load
    }
    #pragma unroll
    for (int r = 0; r < 4; ++r) part[kh][r][col] = acc[r];
    __syncthreads();

    for (int i = threadIdx.x; i < 4*AA; i += 512) {
        const int r = i >> 8, u = i & 255;
        outp[r][u] = part[0][r][u] + part[1][r][u] + p.b2[u];
    }
    __syncthreads();

    const int t = threadIdx.x;
    if (t < 448) {
        const int task = t >> 2, kc = t & 3;
        const int which = (task >= 56) ? 1 : 0;
        const int rem2  = task - which*56;
        const int rr = rem2 / CC, c = rem2 % CC;
        const float* __restrict__ W = which ? p.s1W : p.s0W;
        float s = 0.f;
        #pragma unroll 4
        for (int k = kc*64; k < kc*64 + 64; ++k)
            s = fmaf(outp[rr][k], W[(size_t)k*CC + c], s);
        pp[task][kc] = s;
    }
    __syncthreads();
    if (t < 112) {
        const int which = (t >= 56) ? 1 : 0;
        const int rem2  = t - which*56;
        const int rr = rem2 / CC, c = rem2 % CC;
        const float s = pp[t][0]+pp[t][1]+pp[t][2]+pp[t][3] + (which ? p.s1b : p.s0b)[c];
        (which ? s1o : s0o)[((size_t)net*R_TOT + row0 + rr)*CC + c] = s;
    }
}

// ---------------------------------------------------------------------------
// K3: fused prefix + output fill.  Each block (b,i) recomputes its batch's
// softmax prefix sums in LDS (redundant but removes a dispatch):
//   per c: M = max_k sm0;  E[k] = incl-prefix of exp(sm0-M);  Qe likewise of
//   e*sm1;  mean = sum(sm1)/S.
// Then out[b,i,j,c] = sh1[i,c] + st1[j,c] + uni[c]
//    + (i<=j ? (Qe[j]-Qe[i-1])/(E[j]-E[i-1]) : mean[c])
// grid = 256 blocks ((b,i)), 512 threads
// ---------------------------------------------------------------------------
__global__ __launch_bounds__(512)
void final_kernel(const float* __restrict__ s0w, const float* __restrict__ s1w,
                  const float* __restrict__ uni, float* __restrict__ out)
{
    const int bi = blockIdx.x;        // b*S + i
    const int b = bi >> 7, i = bi & (SS-1);
    const int tid = threadIdx.x;
    const int lane = tid & 63;
    const int k    = tid & 127;       // scan position
    const int wv2  = (tid >> 6) & 1;  // half within scan pair
    const int slot = tid >> 7;        // 0..3: which c this pass

    __shared__ float E[SS*CC];        // 7 KB  (inclusive prefix of e)
    __shared__ float Qe[SS*CC];       // 7 KB  (inclusive prefix of e*sm1)
    __shared__ float red[4][4][2];    // [kind][slot][half]
    __shared__ float mnL[CC], sh1L[CC], uniL[CC];

    if (tid < CC) {
        sh1L[tid] = s1w[(size_t)bi*CC + tid];
        uniL[tid] = uni[tid];
    }

    const float* __restrict__ sm0b = s0w + (size_t)(2*R_TOT + b*SS)*CC;
    const float* __restrict__ sm1b = s1w + (size_t)(2*R_TOT + b*SS)*CC;

    for (int pass = 0; pass < 4; ++pass) {
        const int c = pass*4 + slot;
        float x0 = 0.f, x1 = 0.f, e = 0.f, q = 0.f;
        if (c < CC) {
            x0 = sm0b[(size_t)k*CC + c];
            x1 = sm1b[(size_t)k*CC + c];
            float m = x0;
            #pragma unroll
            for (int off = 32; off >= 1; off >>= 1) m = fmaxf(m, __shfl_xor(m, off));
            float ss = x1;
            #pragma unroll
            for (int off = 32; off >= 1; off >>= 1) ss += __shfl_xor(ss, off);
            if (lane == 0) { red[0][slot][wv2] = m; red[1][slot][wv2] = ss; }
        }
        __syncthreads();
        if (c < CC) {
            const float M = fmaxf(red[0][slot][0], red[0][slot][1]);
            e = __expf(x0 - M);
            q = e * x1;
            #pragma unroll
            for (int off = 1; off <= 32; off <<= 1) {
                const float te = __shfl_up(e, off);
                const float tq = __shfl_up(q, off);
                if (lane >= off) { e += te; q += tq; }
            }
            if (lane == 63) { red[2][slot][wv2] = e; red[3][slot][wv2] = q; }
        }
        __syncthreads();
        if (c < CC) {
            if (wv2 == 1) { e += red[2][slot][0]; q += red[3][slot][0]; }
            E [k*CC + c] = e;
            Qe[k*CC + c] = q;
            if (k == 0) mnL[c] = (red[1][slot][0] + red[1][slot][1]) * (1.f/SS);
        }
        __syncthreads();
    }

    // ---- fill: 1792 outputs as 448 float4 stores
    const float* __restrict__ st1 = s1w + (size_t)(R_TOT + b*SS)*CC;  // [j][c]
    float* __restrict__ o = out + (size_t)bi*SS*CC;
    if (tid < 448) {
        const int e0 = tid * 4;
        float v[4];
        #pragma unroll
        for (int u = 0; u < 4; ++u) {
            const int idx = e0 + u;
            const int j = idx / CC, c = idx - j*CC;
            float add;
            if (i <= j) {
                const float Ei = (i > 0) ? E [(i-1)*CC + c] : 0.f;
                const float Qi = (i > 0) ? Qe[(i-1)*CC + c] : 0.f;
                add = (Qe[j*CC + c] - Qi) / (E[j*CC + c] - Ei);
            } else {
                add = mnL[c];
            }
            v[u] = sh1L[c] + st1[idx] + uniL[c] + add;
        }
        *(float4*)&o[e0] = make_float4(v[0], v[1], v[2], v[3]);
    }
}

extern "C" void kernel_launch(void* const* d_in, const int* in_sizes, int n_in,
                              void* d_out, int out_size, void* d_ws, size_t ws_size,
                              hipStream_t stream)
{
    const float* mem = (const float*)d_in[0];
    AllP P;
    for (int n = 0; n < 3; ++n) {
        const int base = 1 + 8*n;
        P.n[n].W1  = (const float*)d_in[base+0];
        P.n[n].b1  = (const float*)d_in[base+1];
        P.n[n].W2  = (const float*)d_in[base+2];
        P.n[n].b2  = (const float*)d_in[base+3];
        P.n[n].s0W = (const float*)d_in[base+4];
        P.n[n].s0b = (const float*)d_in[base+5];
        P.n[n].s1W = (const float*)d_in[base+6];
        P.n[n].s1b = (const float*)d_in[base+7];
    }
    const float* uni = (const float*)d_in[25];
    float* ws  = (float*)d_ws;
    float* s0  = ws + S0_OFF;
    float* s1  = ws + S1_OFF;
    float* hid = ws + HID_OFF;
    float* out = (float*)d_out;

    hipLaunchKernelGGL(hid_kernel,   dim3(384),    dim3(512), 0, stream, mem, P, hid);
    hipLaunchKernelGGL(out_kernel,   dim3(192),    dim3(512), 0, stream, hid, P, s0, s1);
    hipLaunchKernelGGL(final_kernel, dim3(BB*SS),  dim3(512), 0, stream, s0, s1, uni, out);
}

// Round 5
// 31.090 us; speedup vs baseline: 5.3523x; 1.0667x over previous
//
#include <hip/hip_runtime.h>

#define BB 2
#define SS 128
#define HH 1024
#define AA 256
#define CC 14
#define R_TOT (BB*SS)   // 256 rows per net

struct NetP { const float *W1,*b1,*W2,*b2,*s0W,*s0b,*s1W,*s1b; };
struct AllP { NetP n[3]; };

// ws float offsets
#define S0_OFF 0                         // [3][256][14]
#define S1_OFF (3*R_TOT*CC)

// ---------------------------------------------------------------------------
// K_A: fully fused MLP per 4-row tile.
//   hidL = relu(mem@W1+b1)   (in LDS, never leaves the CU)
//   outL = hidL@W2+b2
//   s0 = outL@s0W+s0b ; s1 = outL@s1W+s1b
// grid = net(3) * rowtile(64 of 4 rows) = 192 blocks, 512 thr = 8 waves.
// Layer 1: wave w owns K-chunk [w*128,w*128+128); lane owns 4 cols (float4).
// Layer 2: wave w owns K-chunk [w*32, w*32+32).
// ---------------------------------------------------------------------------
__global__ __launch_bounds__(512)
void mlp_fused(const float* __restrict__ mem, AllP P,
               float* __restrict__ s0o, float* __restrict__ s1o)
{
    const int bx   = blockIdx.x;
    const int net  = bx >> 6;           // 0..2
    const int rt   = bx & 63;           // 0..63
    const int row0 = rt * 4;
    const NetP p  = P.n[net];
    const int tid  = threadIdx.x;
    const int lane = tid & 63;
    const int wv   = __builtin_amdgcn_readfirstlane(tid >> 6); // 0..7
    const int col4 = 4 * lane;          // float4 column base

    __shared__ float part[8][4][AA];    // 32 KB
    __shared__ float hidL[4][AA];       // 4 KB
    __shared__ float outL[4][AA];       // 4 KB
    __shared__ float pp[112][4];        // 1.75 KB

    // ================= layer 1 =================
    {
        const int k0 = wv * 128;
        const float* __restrict__ W1p = p.W1 + (size_t)k0*AA + col4;
        const float* __restrict__ m0 = mem + (size_t)(row0+0)*HH + k0;
        const float* __restrict__ m1 = mem + (size_t)(row0+1)*HH + k0;
        const float* __restrict__ m2 = mem + (size_t)(row0+2)*HH + k0;
        const float* __restrict__ m3 = mem + (size_t)(row0+3)*HH + k0;
        float4 a0 = {0,0,0,0}, a1 = {0,0,0,0}, a2 = {0,0,0,0}, a3 = {0,0,0,0};
        #pragma unroll 4
        for (int kk = 0; kk < 128; ++kk) {
            const float4 w4 = *(const float4*)(W1p + (size_t)kk*AA);
            const float v0 = m0[kk], v1 = m1[kk], v2 = m2[kk], v3 = m3[kk]; // uniform -> s_load
            a0.x = fmaf(v0, w4.x, a0.x); a0.y = fmaf(v0, w4.y, a0.y);
            a0.z = fmaf(v0, w4.z, a0.z); a0.w = fmaf(v0, w4.w, a0.w);
            a1.x = fmaf(v1, w4.x, a1.x); a1.y = fmaf(v1, w4.y, a1.y);
            a1.z = fmaf(v1, w4.z, a1.z); a1.w = fmaf(v1, w4.w, a1.w);
            a2.x = fmaf(v2, w4.x, a2.x); a2.y = fmaf(v2, w4.y, a2.y);
            a2.z = fmaf(v2, w4.z, a2.z); a2.w = fmaf(v2, w4.w, a2.w);
            a3.x = fmaf(v3, w4.x, a3.x); a3.y = fmaf(v3, w4.y, a3.y);
            a3.z = fmaf(v3, w4.z, a3.z); a3.w = fmaf(v3, w4.w, a3.w);
        }
        *(float4*)&part[wv][0][col4] = a0;
        *(float4*)&part[wv][1][col4] = a1;
        *(float4*)&part[wv][2][col4] = a2;
        *(float4*)&part[wv][3][col4] = a3;
    }
    __syncthreads();
    for (int i = tid; i < 4*AA; i += 512) {
        const int r = i >> 8, u = i & (AA-1);
        float s = p.b1[u];
        #pragma unroll
        for (int w = 0; w < 8; ++w) s += part[w][r][u];
        hidL[r][u] = fmaxf(s, 0.f);
    }
    __syncthreads();

    // ================= layer 2 =================
    {
        const int k0 = wv * 32;
        const float* __restrict__ W2p = p.W2 + (size_t)k0*AA + col4;
        float4 a0 = {0,0,0,0}, a1 = {0,0,0,0}, a2 = {0,0,0,0}, a3 = {0,0,0,0};
        #pragma unroll 4
        for (int kk = 0; kk < 32; ++kk) {
            const float4 w4 = *(const float4*)(W2p + (size_t)kk*AA);
            const float v0 = hidL[0][k0+kk], v1 = hidL[1][k0+kk];  // LDS broadcast
            const float v2 = hidL[2][k0+kk], v3 = hidL[3][k0+kk];
            a0.x = fmaf(v0, w4.x, a0.x); a0.y = fmaf(v0, w4.y, a0.y);
            a0.z = fmaf(v0, w4.z, a0.z); a0.w = fmaf(v0, w4.w, a0.w);
            a1.x = fmaf(v1, w4.x, a1.x); a1.y = fmaf(v1, w4.y, a1.y);
            a1.z = fmaf(v1, w4.z, a1.z); a1.w = fmaf(v1, w4.w, a1.w);
            a2.x = fmaf(v2, w4.x, a2.x); a2.y = fmaf(v2, w4.y, a2.y);
            a2.z = fmaf(v2, w4.z, a2.z); a2.w = fmaf(v2, w4.w, a2.w);
            a3.x = fmaf(v3, w4.x, a3.x); a3.y = fmaf(v3, w4.y, a3.y);
            a3.z = fmaf(v3, w4.z, a3.z); a3.w = fmaf(v3, w4.w, a3.w);
        }
        __syncthreads();   // all layer-1 part reads done before overwrite
        *(float4*)&part[wv][0][col4] = a0;
        *(float4*)&part[wv][1][col4] = a1;
        *(float4*)&part[wv][2][col4] = a2;
        *(float4*)&part[wv][3][col4] = a3;
    }
    __syncthreads();
    for (int i = tid; i < 4*AA; i += 512) {
        const int r = i >> 8, u = i & (AA-1);
        float s = p.b2[u];
        #pragma unroll
        for (int w = 0; w < 8; ++w) s += part[w][r][u];
        outL[r][u] = s;
    }
    __syncthreads();

    // ================= projections to C=14 =================
    if (tid < 448) {
        const int task = tid >> 2, kc = tid & 3;
        const int which = (task >= 56) ? 1 : 0;
        const int rem2  = task - which*56;
        const int rr = rem2 / CC, c = rem2 % CC;
        const float* __restrict__ W = which ? p.s1W : p.s0W;
        float s = 0.f;
        #pragma unroll 4
        for (int k = kc*64; k < kc*64 + 64; ++k)
            s = fmaf(outL[rr][k], W[(size_t)k*CC + c], s);
        pp[task][kc] = s;
    }
    __syncthreads();
    if (tid < 112) {
        const int which = (tid >= 56) ? 1 : 0;
        const int rem2  = tid - which*56;
        const int rr = rem2 / CC, c = rem2 % CC;
        const float s = pp[tid][0]+pp[tid][1]+pp[tid][2]+pp[tid][3]
                      + (which ? p.s1b : p.s0b)[c];
        (which ? s1o : s0o)[((size_t)net*R_TOT + row0 + rr)*CC + c] = s;
    }
}

// ---------------------------------------------------------------------------
// K_B: fused prefix + output fill (unchanged from R4 — proven).
// ---------------------------------------------------------------------------
__global__ __launch_bounds__(512)
void final_kernel(const float* __restrict__ s0w, const float* __restrict__ s1w,
                  const float* __restrict__ uni, float* __restrict__ out)
{
    const int bi = blockIdx.x;        // b*S + i
    const int b = bi >> 7, i = bi & (SS-1);
    const int tid = threadIdx.x;
    const int lane = tid & 63;
    const int k    = tid & 127;       // scan position
    const int wv2  = (tid >> 6) & 1;  // half within scan pair
    const int slot = tid >> 7;        // 0..3: which c this pass

    __shared__ float E[SS*CC];        // 7 KB
    __shared__ float Qe[SS*CC];       // 7 KB
    __shared__ float red[4][4][2];
    __shared__ float mnL[CC], sh1L[CC], uniL[CC];

    if (tid < CC) {
        sh1L[tid] = s1w[(size_t)bi*CC + tid];
        uniL[tid] = uni[tid];
    }

    const float* __restrict__ sm0b = s0w + (size_t)(2*R_TOT + b*SS)*CC;
    const float* __restrict__ sm1b = s1w + (size_t)(2*R_TOT + b*SS)*CC;

    for (int pass = 0; pass < 4; ++pass) {
        const int c = pass*4 + slot;
        float x0 = 0.f, x1 = 0.f, e = 0.f, q = 0.f;
        if (c < CC) {
            x0 = sm0b[(size_t)k*CC + c];
            x1 = sm1b[(size_t)k*CC + c];
            float m = x0;
            #pragma unroll
            for (int off = 32; off >= 1; off >>= 1) m = fmaxf(m, __shfl_xor(m, off));
            float ss = x1;
            #pragma unroll
            for (int off = 32; off >= 1; off >>= 1) ss += __shfl_xor(ss, off);
            if (lane == 0) { red[0][slot][wv2] = m; red[1][slot][wv2] = ss; }
        }
        __syncthreads();
        if (c < CC) {
            const float M = fmaxf(red[0][slot][0], red[0][slot][1]);
            e = __expf(x0 - M);
            q = e * x1;
            #pragma unroll
            for (int off = 1; off <= 32; off <<= 1) {
                const float te = __shfl_up(e, off);
                const float tq = __shfl_up(q, off);
                if (lane >= off) { e += te; q += tq; }
            }
            if (lane == 63) { red[2][slot][wv2] = e; red[3][slot][wv2] = q; }
        }
        __syncthreads();
        if (c < CC) {
            if (wv2 == 1) { e += red[2][slot][0]; q += red[3][slot][0]; }
            E [k*CC + c] = e;
            Qe[k*CC + c] = q;
            if (k == 0) mnL[c] = (red[1][slot][0] + red[1][slot][1]) * (1.f/SS);
        }
        __syncthreads();
    }

    const float* __restrict__ st1 = s1w + (size_t)(R_TOT + b*SS)*CC;  // [j][c]
    float* __restrict__ o = out + (size_t)bi*SS*CC;
    if (tid < 448) {
        const int e0 = tid * 4;
        float v[4];
        #pragma unroll
        for (int u = 0; u < 4; ++u) {
            const int idx = e0 + u;
            const int j = idx / CC, c = idx - j*CC;
            float add;
            if (i <= j) {
                const float Ei = (i > 0) ? E [(i-1)*CC + c] : 0.f;
                const float Qi = (i > 0) ? Qe[(i-1)*CC + c] : 0.f;
                add = (Qe[j*CC + c] - Qi) / (E[j*CC + c] - Ei);
            } else {
                add = mnL[c];
            }
            v[u] = sh1L[c] + st1[idx] + uniL[c] + add;
        }
        *(float4*)&o[e0] = make_float4(v[0], v[1], v[2], v[3]);
    }
}

extern "C" void kernel_launch(void* const* d_in, const int* in_sizes, int n_in,
                              void* d_out, int out_size, void* d_ws, size_t ws_size,
                              hipStream_t stream)
{
    const float* mem = (const float*)d_in[0];
    AllP P;
    for (int n = 0; n < 3; ++n) {
        const int base = 1 + 8*n;
        P.n[n].W1  = (const float*)d_in[base+0];
        P.n[n].b1  = (const float*)d_in[base+1];
        P.n[n].W2  = (const float*)d_in[base+2];
        P.n[n].b2  = (const float*)d_in[base+3];
        P.n[n].s0W = (const float*)d_in[base+4];
        P.n[n].s0b = (const float*)d_in[base+5];
        P.n[n].s1W = (const float*)d_in[base+6];
        P.n[n].s1b = (const float*)d_in[base+7];
    }
    const float* uni = (const float*)d_in[25];
    float* ws  = (float*)d_ws;
    float* s0  = ws + S0_OFF;
    float* s1  = ws + S1_OFF;
    float* out = (float*)d_out;

    hipLaunchKernelGGL(mlp_fused,    dim3(192),   dim3(512), 0, stream, mem, P, s0, s1);
    hipLaunchKernelGGL(final_kernel, dim3(BB*SS), dim3(512), 0, stream, s0, s1, uni, out);
}